// Round 22
// baseline (446.841 us; speedup 1.0000x reference)
//
#include <hip/hip_runtime.h>
#include <math.h>

typedef unsigned int U32;
typedef unsigned long long U64;

#define NBOX   90000
#define NPIX   10000
#define KDIM   1024
#define CBOT   512
#define PRE_N  6000
#define POST_N 300
#define NWORD  94      // ceil(6000/64)
#define MROWS  6016    // 94*64 rows allocated per column in maskT
#define NTIE   3072    // tie-buffer capacity (ties at T are O(1) for this data)
#define HP     14      // pixels per k_heads block
#define CSPL   750     // rank column-slice (8 slices x 750 = 6000)

// ---------------- workspace layout (byte offsets, all 16B aligned) ----------
#define OFF_H       0ULL          // 10000*512*4   = 20480000
#define OFF_BOXES   20480000ULL   // 90000*4*4     = 1440000
#define OFF_KEYS    21920000ULL   // 90000*4 = 360000; rank[6000] overlays
                                  // this region once keys go dead (post-compact)
#define OFF_MASKT   22280000ULL   // 94*6016*8     = 4524032 (column-major)
#define OFF_SEL     26804032ULL   // 6000*8        = 48000
#define OFF_SBOX    26852032ULL   // 6000*4*4      = 96000
#define OFF_VALIDW  26948032ULL   // 94*8 -> 768
#define OFF_KEEPW   26948800ULL   // 768 (unused since R17 fusion)
#define OFF_CNT     26950592ULL   // 64*4 = 256
#define OFF_HIST4   26950848ULL   // 4 levels * 256 * 4 = 4096
#define OFF_TIE     26954944ULL   // 3072*4 = 12288 -> ends at WS_NEED
#define WS_NEED     26967232ULL

// cnt[] slots: 8=n_gt atomic  9=n_tie atomic

// ============================================================================
// Local radix-scan chain (R17): every consumer block recomputes digit
// selection from the per-level global histograms. Parallel 256-wide reverse
// inclusive scan + atomicMax digit pick == old serial k_scan semantics.
// res[0]=prefix res[1]=target(need) res[2]=cgt res[3]=digit scratch.
// ============================================================================
__device__ __forceinline__ void scan_levels(
    const U32* __restrict__ histg, int levels, int t,
    U32* lh, U32* sfx, volatile U32* res)
{
  if (t == 0) { res[0] = 0; res[1] = PRE_N; res[2] = 0; }
  __syncthreads();
  for (int L = 0; L < levels; ++L) {
    if (t < 256) { U32 h = histg[L * 256 + t]; lh[t] = h; sfx[t] = h; }
    if (t == 0) res[3] = 0;
    __syncthreads();
    for (int off = 1; off < 256; off <<= 1) {
      U32 v = 0;
      if (t < 256) v = sfx[t] + ((t + off < 256) ? sfx[t + off] : 0);
      __syncthreads();
      if (t < 256) sfx[t] = v;
      __syncthreads();
    }
    if (t > 0 && t < 256 && sfx[t] >= res[1]) atomicMax((U32*)&res[3], (U32)t);
    __syncthreads();
    if (t == 0) {
      U32 d = res[3];
      U32 cum = (d < 255) ? sfx[d + 1] : 0;
      res[0] |= d << (24 - 8 * L);
      res[1] = res[1] - cum;
      res[2] += cum;
    }
    __syncthreads();
  }
}

// ============================================================================
// K1: h = relu(feats @ W_b + b_b)  fp32, 64x64 tile, 4x4 acc/thread, BK=16.
// EXACT R18 version (measured 157us, VGPR=40, occ 37%, FETCH 69MB). FROZEN:
// R15 (dbuf) spilled acc -> 10x; R19 (B-from-L2) regressed 30%; R18 is the
// measured local optimum for this toolchain. XCD remap keeps A L2-resident.
// Also zero-inits hist4/cnt/validw (block 0 only).
// ============================================================================
__global__ __launch_bounds__(256, 4) void k_gemm1(
    const float* __restrict__ A, const float* __restrict__ W,
    const float* __restrict__ bias, float* __restrict__ H,
    U32* __restrict__ hist4, U32* __restrict__ cnt, U32* __restrict__ validw32)
{
  int t = threadIdx.x;
  if (blockIdx.x == 0) {
    hist4[t] = 0; hist4[t + 256] = 0; hist4[t + 512] = 0; hist4[t + 768] = 0;
    if (t < 64)  cnt[t] = 0u;
    if (t < 188) validw32[t] = 0;
  }
  int bid = blockIdx.x;
  int c = bid & 7;                 // XCD under round-robin dispatch
  int s = bid >> 3;                // 0..159
  int x = s / 20;                  // 0..7   column block
  int yy = c * 20 + (s % 20);      // 0..159 row block; XCD-local A slab
  if (yy >= 157) return;           // 24 dead blocks
  __shared__ float As[16][68];    // [k][m], pad keeps 16B alignment
  __shared__ float Bs[16][68];    // [k][n]
  int m0 = yy * 64, n0 = x * 64;
  int tm = t >> 4, tn = t & 15;
  int ar = t >> 2, ac = (t & 3) << 2;   // A stage: row ar, cols ac..ac+3
  int bk = t >> 4, bc = (t & 15) << 2;  // B stage: row bk, cols bc..bc+3
  float acc[4][4];
#pragma unroll
  for (int i = 0; i < 4; ++i)
#pragma unroll
    for (int j = 0; j < 4; ++j) acc[i][j] = 0.f;

  // prologue: first tile's loads
  int arow = m0 + ar;
  float4 a0 = make_float4(0.f,0.f,0.f,0.f);
  if (arow < NPIX) a0 = *(const float4*)&A[(size_t)arow * KDIM + ac];
  float4 b0 = *(const float4*)&W[(size_t)bk * CBOT + n0 + bc];

  for (int k0 = 0; k0 < KDIM; k0 += 16) {
    __syncthreads();                 // prior FMA readers done
    As[ac+0][ar] = a0.x; As[ac+1][ar] = a0.y;
    As[ac+2][ar] = a0.z; As[ac+3][ar] = a0.w;
    *(float4*)&Bs[bk][bc] = b0;
    __syncthreads();
    if (k0 + 16 < KDIM) {            // issue next-tile loads BEFORE FMA loop
      int kn = k0 + 16;
      if (arow < NPIX) a0 = *(const float4*)&A[(size_t)arow * KDIM + kn + ac];
      b0 = *(const float4*)&W[(size_t)(kn + bk) * CBOT + n0 + bc];
    }
#pragma unroll
    for (int kk = 0; kk < 16; ++kk) {
      float4 av = *(float4*)&As[kk][tm*4];       // 16-lane broadcast groups
      float4 bv = *(float4*)&Bs[kk][tn*4];       // 2-way aliasing: free
      float am[4] = {av.x, av.y, av.z, av.w};
      float bm[4] = {bv.x, bv.y, bv.z, bv.w};
#pragma unroll
      for (int i = 0; i < 4; ++i)
#pragma unroll
        for (int j = 0; j < 4; ++j)
          acc[i][j] = fmaf(am[i], bm[j], acc[i][j]);
    }
  }
  float4 bb = *(const float4*)&bias[n0 + tn*4];
  float bm[4] = {bb.x, bb.y, bb.z, bb.w};
#pragma unroll
  for (int i = 0; i < 4; ++i) {
    int r = m0 + tm*4 + i;
    if (r < NPIX) {
      float4 o;
      o.x = fmaxf(acc[i][0] + bm[0], 0.f);
      o.y = fmaxf(acc[i][1] + bm[1], 0.f);
      o.z = fmaxf(acc[i][2] + bm[2], 0.f);
      o.w = fmaxf(acc[i][3] + bm[3], 0.f);
      *(float4*)&H[(size_t)r * CBOT + n0 + tn*4] = o;
    }
  }
}

// ============================================================================
// K2: cls = sigmoid(h@W_cls+b_cls), reg = h@W_reg+b_reg.
// R20 layout: 14 pixels x 18 threads (9 cls scalar + 9 reg float4 threads).
// Per-output FMA chains ascending-k -> outputs bitwise unchanged.
// ============================================================================
__global__ __launch_bounds__(256) void k_heads(
    const float* __restrict__ H, const float* __restrict__ Wc,
    const float* __restrict__ bc, const float* __restrict__ Wr,
    const float* __restrict__ br, float* __restrict__ outCls,
    float* __restrict__ outReg)
{
  __shared__ float hs[HP][516];
  int t = threadIdx.x;
  int p0 = blockIdx.x * HP;
  for (int q = t; q < HP * 128; q += 256) {
    int row = q >> 7, off = (q & 127) << 2;
    if (p0 + row < NPIX)
      *(float4*)&hs[row][off] = *(const float4*)&H[(size_t)(p0 + row) * CBOT + off];
  }
  __syncthreads();
  if (t < HP * 18) {
    int pl = t / 18, c = t % 18;
    int p = p0 + pl;
    if (p < NPIX) {
      const float* hrow = hs[pl];
      if (c < 9) {                       // cls channel c (scalar chain)
        float s = 0.f;
        for (int k = 0; k < CBOT; k += 4) {
          float4 hv = *(const float4*)&hrow[k];
          s = fmaf(hv.x, Wc[(size_t)(k+0)*9 + c], s);
          s = fmaf(hv.y, Wc[(size_t)(k+1)*9 + c], s);
          s = fmaf(hv.z, Wc[(size_t)(k+2)*9 + c], s);
          s = fmaf(hv.w, Wc[(size_t)(k+3)*9 + c], s);
        }
        s += bc[c];
        outCls[(size_t)p*9 + c] = 1.f / (1.f + expf(-s));
      } else {                           // reg channels g..g+3 (float4 loads)
        int g = (c - 9) << 2;
        float4 s4 = make_float4(0.f, 0.f, 0.f, 0.f);
        for (int k = 0; k < CBOT; k += 4) {
          float4 hv = *(const float4*)&hrow[k];
          float4 w0 = *(const float4*)&Wr[(size_t)(k+0)*36 + g];
          float4 w1 = *(const float4*)&Wr[(size_t)(k+1)*36 + g];
          float4 w2 = *(const float4*)&Wr[(size_t)(k+2)*36 + g];
          float4 w3 = *(const float4*)&Wr[(size_t)(k+3)*36 + g];
          s4.x = fmaf(hv.x, w0.x, s4.x); s4.y = fmaf(hv.x, w0.y, s4.y);
          s4.z = fmaf(hv.x, w0.z, s4.z); s4.w = fmaf(hv.x, w0.w, s4.w);
          s4.x = fmaf(hv.y, w1.x, s4.x); s4.y = fmaf(hv.y, w1.y, s4.y);
          s4.z = fmaf(hv.y, w1.z, s4.z); s4.w = fmaf(hv.y, w1.w, s4.w);
          s4.x = fmaf(hv.z, w2.x, s4.x); s4.y = fmaf(hv.z, w2.y, s4.y);
          s4.z = fmaf(hv.z, w2.z, s4.z); s4.w = fmaf(hv.z, w2.w, s4.w);
          s4.x = fmaf(hv.w, w3.x, s4.x); s4.y = fmaf(hv.w, w3.y, s4.y);
          s4.z = fmaf(hv.w, w3.z, s4.z); s4.w = fmaf(hv.w, w3.w, s4.w);
        }
        float4 bb = *(const float4*)&br[g];
        s4.x += bb.x; s4.y += bb.y; s4.z += bb.z; s4.w += bb.w;
        *(float4*)&outReg[(size_t)p*36 + g] = s4;
      }
    }
  }
}

// ============================================================================
// K3: decode boxes, size filter, sortable keys, level-0 histogram
// ============================================================================
__global__ __launch_bounds__(256) void k_decode(
    const float* __restrict__ outCls, const float* __restrict__ outReg,
    const float* __restrict__ ancs, float* __restrict__ boxes,
    U32* __restrict__ keys, U32* __restrict__ hist4)
{
  __shared__ U32 lh[256];
  int t = threadIdx.x;
  int tid = blockIdx.x * 256 + t;
  lh[t] = 0;
  __syncthreads();
  if (tid < NBOX) {
    float sc = outCls[tid];
    float4 of = *(const float4*)&outReg[(size_t)tid*4];
    float4 an = *(const float4*)&ancs[(size_t)tid*4];
    float cx = an.x + of.x * an.z;
    float cy = an.y + of.y * an.w;
    float ww = an.z * expf(of.z);
    float hh = an.w * expf(of.w);
    float x1 = fminf(fmaxf(cx - ww * 0.5f, 0.f), 1.f);
    float y1 = fminf(fmaxf(cy - hh * 0.5f, 0.f), 1.f);
    float x2 = fminf(fmaxf(cx + ww * 0.5f, 0.f), 1.f);
    float y2 = fminf(fmaxf(cy + hh * 0.5f, 0.f), 1.f);
    bool ok = ((x2 - x1) * 100.f >= 1.f) && ((y2 - y1) * 100.f >= 1.f);
    float msc = ok ? sc : -1.f;
    U32 u = __float_as_uint(msc);
    U32 key = (u & 0x80000000u) ? ~u : (u | 0x80000000u);
    keys[tid] = key;
    *(float4*)&boxes[(size_t)tid*4] = make_float4(x1, y1, x2, y2);
    atomicAdd(&lh[key >> 24], 1u);
  }
  __syncthreads();
  if (lh[t]) atomicAdd(&hist4[t], lh[t]);
}

// ============================================================================
// K5: filtered histogram for levels 1..3; prefix recomputed locally.
// ============================================================================
__global__ __launch_bounds__(256) void k_hist(
    const U32* __restrict__ keys, U32* __restrict__ hist4, int level)
{
  __shared__ U32 lh[256];
  __shared__ U32 sfx[256];
  __shared__ U32 res[4];
  int t = threadIdx.x;
  scan_levels(hist4, level, t, lh, sfx, res);
  U32 prefix = res[0];
  lh[t] = 0;
  __syncthreads();
  int tid = blockIdx.x * 256 + t;
  if (tid < NBOX) {
    U32 k = keys[tid];
    int shift = 32 - 8*level;
    if ((k >> shift) == (prefix >> shift)) {
      U32 bin = (k >> (24 - 8*level)) & 0xFFu;
      atomicAdd(&lh[bin], 1u);
    }
  }
  __syncthreads();
  if (lh[t]) atomicAdd(&hist4[level * 256 + t], lh[t]);
}

// ============================================================================
// K6: compact: keys > T -> sel; keys == T -> tie buffer. T local.
// (Last reader of keys[]; rank[] overlays that region afterwards.)
// ============================================================================
__global__ __launch_bounds__(256) void k_compact(
    const U32* __restrict__ keys, const U32* __restrict__ hist4,
    U32* __restrict__ cnt, U64* __restrict__ sel, U32* __restrict__ tiebuf)
{
  __shared__ U32 lh[256];
  __shared__ U32 sfx[256];
  __shared__ U32 res[4];
  int t = threadIdx.x;
  scan_levels(hist4, 4, t, lh, sfx, res);
  U32 T = res[0];
  int tid = blockIdx.x * 256 + t;
  if (tid >= NBOX) return;
  U32 k = keys[tid];
  if (k > T) {
    U32 p = atomicAdd(&cnt[8], 1u);
    sel[p] = ((U64)k << 32) | (U64)(0xFFFFFFFFu - (U32)tid);
  } else if (k == T) {
    U32 p = atomicAdd(&cnt[9], 1u);
    if (p < NTIE) tiebuf[p] = (U32)tid;
  }
}

// ============================================================================
// K7: resolve ==T ties by smallest index; need/cgt/T local.
// Also zeroes rank[6000] (overlaid on dead keys region) for k_rankp.
// ============================================================================
__global__ __launch_bounds__(256) void k_ties(
    const U32* __restrict__ hist4, U32* __restrict__ cnt,
    const U32* __restrict__ tiebuf, U64* __restrict__ sel,
    U32* __restrict__ rank)
{
  __shared__ U32 lh[256];
  __shared__ U32 sfx[256];
  __shared__ U32 res[4];
  __shared__ U32 tb[NTIE];
  int t = threadIdx.x;
  for (int j = t; j < PRE_N; j += 256) rank[j] = 0;   // zero rank array
  scan_levels(hist4, 4, t, lh, sfx, res);
  U32 T    = res[0];
  U32 need = res[1];
  U32 cgt  = res[2];
  U32 m = cnt[9]; if (m > (U32)NTIE) m = (U32)NTIE;
  for (U32 j = t; j < m; j += 256) tb[j] = tiebuf[j];
  __syncthreads();
  for (U32 x = t; x < m; x += 256) {
    U32 my = tb[x];
    U32 r = 0;
    for (U32 j = 0; j < m; ++j) r += (tb[j] < my) ? 1u : 0u;
    if (r < need) sel[cgt + r] = ((U64)T << 32) | (U64)(0xFFFFFFFFu - my);
  }
}

// ============================================================================
// K8a: partial ranks. Grid (24, 8): block (bi,bj) compares candidates
// [256*bi, 256*bi+256) against column slice [750*bj, 750*bj+750) staged in
// LDS; integer atomicAdd partials (order-invariant => deterministic).
// ============================================================================
__global__ __launch_bounds__(256) void k_rankp(
    const U64* __restrict__ sel, U32* __restrict__ rank)
{
  __shared__ __align__(16) U64 ss[CSPL + 2];   // +2 pad (zeros, never > C)
  int t = threadIdx.x;
  int j0 = blockIdx.y * CSPL;
  for (int j = t; j < CSPL + 2; j += 256)
    ss[j] = (j < CSPL) ? sel[j0 + j] : 0ull;
  __syncthreads();
  int i = blockIdx.x * 256 + t;
  if (i >= PRE_N) return;
  U64 C = sel[i];
  int r = 0;
  for (int j = 0; j < CSPL; j += 4) {          // 750 = 187*4 + 2: pad covers
    ulonglong2 v0 = *(const ulonglong2*)&ss[j];
    ulonglong2 v1 = *(const ulonglong2*)&ss[j + 2];
    r += (int)(v0.x > C) + (int)(v0.y > C) + (int)(v1.x > C) + (int)(v1.y > C);
  }
  if (r) atomicAdd(&rank[i], (U32)r);
}

// ============================================================================
// K8b: placement by final rank -> sorted boxes + packed valid bits.
// ============================================================================
__global__ __launch_bounds__(256) void k_place(
    const U64* __restrict__ sel, const U32* __restrict__ rank,
    const float* __restrict__ boxes, float* __restrict__ sboxes,
    U64* __restrict__ validw)
{
  int i = blockIdx.x * 256 + threadIdx.x;
  if (i >= PRE_N) return;
  U64 C = sel[i];
  U32 r = rank[i];
  U32 key = (U32)(C >> 32);
  U32 idx = 0xFFFFFFFFu - (U32)(C & 0xFFFFFFFFull);
  *(float4*)&sboxes[(size_t)r*4] = *(const float4*)&boxes[(size_t)idx*4];
  if (key & 0x80000000u)
    atomicOr(&validw[r >> 6], 1ull << (r & 63));
}

// ============================================================================
// K9: IoU > 0.7 bitmask, COLUMN-word-major, upper triangle + diagonal only.
// Rows 6000..6015 in touched blocks written as 0.
// ============================================================================
__global__ __launch_bounds__(256) void k_mask(
    const float* __restrict__ sboxes, U64* __restrict__ maskT)
{
  int cw = blockIdx.x, rg = blockIdx.y;
  if (rg < cw) return;                       // lower triangle unused by NMS
  int t = threadIdx.x;
  int lane = t & 63, wv = t >> 6;
  int col = cw * 64 + lane;
  int cc = (col < PRE_N) ? col : (PRE_N - 1);
  float4 cb = *(const float4*)&sboxes[(size_t)cc*4];
  float areaC = (cb.z - cb.x) * (cb.w - cb.y);
  bool colok = (col < PRE_N);
  for (int rr = wv; rr < 64; rr += 4) {
    int row = rg * 64 + rr;
    U64 word = 0;
    if (row < PRE_N) {
      float4 rb = *(const float4*)&sboxes[(size_t)row*4];
      float areaR = (rb.z - rb.x) * (rb.w - rb.y);
      float ix1 = fmaxf(rb.x, cb.x), iy1 = fmaxf(rb.y, cb.y);
      float ix2 = fminf(rb.z, cb.z), iy2 = fminf(rb.w, cb.w);
      float inter = fmaxf(ix2 - ix1, 0.f) * fmaxf(iy2 - iy1, 0.f);
      float uni = areaR + areaC - inter;
      float iou = inter / fmaxf(uni, 1e-9f);
      word = __ballot(colok && (iou > 0.7f));
    }
    if (lane == 0) maskT[(size_t)cw * MROWS + row] = word;
  }
}

// ============================================================================
// K10: sequential-equivalent NMS — 8 WAVES, barrier phases, hoisted apply
// loads, fused proposal output. R22: load/apply groups bounded by
// ng = ceil((PRE_N-base)/512) (wave-uniform) — late chunks skip dead groups
// (1128 -> ~550 issued groups). Decide logic/barriers unchanged;
// bitwise-deterministic, reference scan order.
// ============================================================================
__global__ __launch_bounds__(512, 1) void k_nms(
    const U64* __restrict__ maskT, const U64* __restrict__ validw,
    const float* __restrict__ sboxes, float* __restrict__ prop)
{
  __shared__ U32 sup[MROWS];
  __shared__ U64 vws[NWORD];
  __shared__ U64 kwS[NWORD];
  __shared__ U32 pre[NWORD + 1];
  __shared__ U64 kwsh;
  int t = threadIdx.x;                       // 0..511
  int wave = t >> 6, lane = t & 63;
  for (int i = t; i < MROWS; i += 512) sup[i] = 0;
  if (t < NWORD) vws[t] = validw[t];
  U64 low = (lane == 0) ? 0ull : (~0ull >> (64 - lane));
  U64 intra = (wave == 0) ? maskT[lane] : 0ull;   // chunk 0 diagonal word
  __syncthreads();
  for (int c = 0; c < NWORD; ++c) {
    const U64* colp = maskT + (size_t)c * MROWS;
    int base = (c + 1) * 64;
    int ng = (PRE_N - base + 511) >> 9;      // groups needed (uniform), 0..12
    // ---- hoisted apply loads (independent of decide; dead groups skipped) --
    U64 m[12];
#pragma unroll
    for (int q = 0; q < 12; ++q) {
      if (q < ng) {
        int i = base + q * 512 + t;
        int ic = (i > MROWS - 1) ? (MROWS - 1) : i;
        m[q] = colp[ic];
      } else {
        m[q] = 0;
      }
    }
    if (wave == 0) {
      // ---- decide (wave-0 local; ballots are per-wave) ----
      U64 vw = vws[c];
      bool alive = (((vw >> lane) & 1ull) != 0ull) && (sup[c * 64 + lane] == 0u);
      U64 aliveW = __ballot(alive);
      bool myconf = alive && ((intra & aliveW & low) != 0ull);
      U64 confW = __ballot(myconf);
      U64 keep = aliveW & ~confW;            // non-conflicted alive are kept
      U64 rem = confW;                       // resolve conflicted ascending
      while (rem) {
        int b = __ffsll((unsigned long long)rem) - 1;
        rem &= rem - 1;
        U64 Z = __ballot((intra & keep & low) == 0ull);
        if ((Z >> b) & 1ull) keep |= (1ull << b);
      }
      if (lane == 0) { kwS[c] = keep; kwsh = keep; }
      if (c + 1 < NWORD)                     // prefetch next diagonal word
        intra = maskT[(size_t)(c + 1) * MROWS + (c + 1) * 64 + lane];
    }
    __syncthreads();                         // kwsh + sup reads ordered
    U64 keep = kwsh;                         // 0 -> stores self-disable
#pragma unroll
    for (int q = 0; q < 12; ++q) {
      if (q < ng) {
        int i = base + q * 512 + t;
        if (i < PRE_N && (m[q] & keep)) sup[i] = 1u;
      }
    }
    __syncthreads();                         // sup[] complete before decide c+1
  }
  // ---- fused proposal output ----
  if (t == 0) {
    U32 s = 0;
    for (int w = 0; w < NWORD; ++w) { pre[w] = s; s += (U32)__popcll(kwS[w]); }
    pre[NWORD] = s;
  }
  for (int x = t; x < POST_N * 4; x += 512) prop[x] = 0.f;
  __syncthreads();
  for (int i = t; i < PRE_N; i += 512) {
    int w = i >> 6, b = i & 63;
    if ((kwS[w] >> b) & 1ull) {
      U64 lowb = (b == 0) ? 0ull : (~0ull >> (64 - b));
      U32 r = pre[w] + (U32)__popcll(kwS[w] & lowb);
      if (r < POST_N)
        *(float4*)&prop[(size_t)r*4] = *(const float4*)&sboxes[(size_t)i*4];
    }
  }
}

// ============================================================================
extern "C" void kernel_launch(void* const* d_in, const int* in_sizes, int n_in,
                              void* d_out, int out_size, void* d_ws, size_t ws_size,
                              hipStream_t stream)
{
  (void)in_sizes; (void)n_in; (void)out_size;
  if (ws_size < WS_NEED) return;   // scratch too small; bail safely

  const float* feats = (const float*)d_in[0];
  const float* ancs  = (const float*)d_in[1];
  const float* W_b   = (const float*)d_in[3];
  const float* b_b   = (const float*)d_in[4];
  const float* W_cls = (const float*)d_in[5];
  const float* b_cls = (const float*)d_in[6];
  const float* W_reg = (const float*)d_in[7];
  const float* b_reg = (const float*)d_in[8];

  float* out    = (float*)d_out;
  float* outCls = out;                 // 90000
  float* outReg = out + 90000;         // 360000
  float* prop   = out + 450000;        // 1200

  char* ws = (char*)d_ws;
  float* H      = (float*)(ws + OFF_H);
  float* boxes  = (float*)(ws + OFF_BOXES);
  U32*   keys   = (U32*)  (ws + OFF_KEYS);
  U32*   rankb  = (U32*)  (ws + OFF_KEYS);   // overlays keys (dead post-compact)
  U64*   maskT  = (U64*)  (ws + OFF_MASKT);
  U64*   sel    = (U64*)  (ws + OFF_SEL);
  float* sboxes = (float*)(ws + OFF_SBOX);
  U64*   validw = (U64*)  (ws + OFF_VALIDW);
  U32*   cnt    = (U32*)  (ws + OFF_CNT);
  U32*   hist4  = (U32*)  (ws + OFF_HIST4);
  U32*   tiebuf = (U32*)  (ws + OFF_TIE);

  k_gemm1<<<dim3(1280), dim3(256), 0, stream>>>(feats, W_b, b_b, H,
                                                hist4, cnt, (U32*)validw);
  k_heads<<<dim3((NPIX + HP - 1) / HP), dim3(256), 0, stream>>>(
      H, W_cls, b_cls, W_reg, b_reg, outCls, outReg);
  k_decode<<<dim3(352), dim3(256), 0, stream>>>(outCls, outReg, ancs,
                                                boxes, keys, hist4);
  for (int lv = 1; lv <= 3; ++lv)
    k_hist<<<dim3(352), dim3(256), 0, stream>>>(keys, hist4, lv);
  k_compact<<<dim3(352), dim3(256), 0, stream>>>(keys, hist4, cnt, sel, tiebuf);
  k_ties<<<dim3(1), dim3(256), 0, stream>>>(hist4, cnt, tiebuf, sel, rankb);
  k_rankp<<<dim3(24, 8), dim3(256), 0, stream>>>(sel, rankb);
  k_place<<<dim3(24), dim3(256), 0, stream>>>(sel, rankb, boxes, sboxes, validw);
  k_mask<<<dim3(94, 94), dim3(256), 0, stream>>>(sboxes, maskT);
  k_nms<<<dim3(1), dim3(512), 0, stream>>>(maskT, validw, sboxes, prop);
}

// Round 23
// 435.725 us; speedup vs baseline: 1.0255x; 1.0255x over previous
//
#include <hip/hip_runtime.h>
#include <math.h>

typedef unsigned int U32;
typedef unsigned long long U64;

#define NBOX   90000
#define NPIX   10000
#define KDIM   1024
#define CBOT   512
#define PRE_N  6000
#define POST_N 300
#define NWORD  94      // ceil(6000/64)
#define MROWS  6016    // 94*64 rows allocated per column in maskT
#define NTIE   3072    // tie-buffer capacity (ties at T are O(1) for this data)
#define HP     14      // pixels per k_heads block
#define CSPL   750     // rank column-slice (8 slices x 750 = 6000)

// ---------------- workspace layout (byte offsets, all 16B aligned) ----------
#define OFF_H       0ULL          // 10000*512*4   = 20480000
#define OFF_BOXES   20480000ULL   // 90000*4*4     = 1440000
#define OFF_KEYS    21920000ULL   // 90000*4 = 360000; rank[6000] overlays
                                  // this region once keys go dead (post-compact)
#define OFF_MASKT   22280000ULL   // 94*6016*8     = 4524032 (column-major)
#define OFF_SEL     26804032ULL   // 6000*8        = 48000
#define OFF_SBOX    26852032ULL   // 6000*4*4      = 96000
#define OFF_VALIDW  26948032ULL   // 94*8 -> 768
#define OFF_KEEPW   26948800ULL   // 768 (unused since R17 fusion)
#define OFF_CNT     26950592ULL   // 64*4 = 256
#define OFF_HIST4   26950848ULL   // 4 levels * 256 * 4 = 4096
#define OFF_TIE     26954944ULL   // 3072*4 = 12288 -> ends at WS_NEED
#define WS_NEED     26967232ULL

// cnt[] slots: 8=n_gt atomic  9=n_tie atomic

// ============================================================================
// Local radix-scan chain (R17): every consumer block recomputes digit
// selection from the per-level global histograms. Parallel 256-wide reverse
// inclusive scan + atomicMax digit pick == old serial k_scan semantics.
// res[0]=prefix res[1]=target(need) res[2]=cgt res[3]=digit scratch.
// ============================================================================
__device__ __forceinline__ void scan_levels(
    const U32* __restrict__ histg, int levels, int t,
    U32* lh, U32* sfx, volatile U32* res)
{
  if (t == 0) { res[0] = 0; res[1] = PRE_N; res[2] = 0; }
  __syncthreads();
  for (int L = 0; L < levels; ++L) {
    if (t < 256) { U32 h = histg[L * 256 + t]; lh[t] = h; sfx[t] = h; }
    if (t == 0) res[3] = 0;
    __syncthreads();
    for (int off = 1; off < 256; off <<= 1) {
      U32 v = 0;
      if (t < 256) v = sfx[t] + ((t + off < 256) ? sfx[t + off] : 0);
      __syncthreads();
      if (t < 256) sfx[t] = v;
      __syncthreads();
    }
    if (t > 0 && t < 256 && sfx[t] >= res[1]) atomicMax((U32*)&res[3], (U32)t);
    __syncthreads();
    if (t == 0) {
      U32 d = res[3];
      U32 cum = (d < 255) ? sfx[d + 1] : 0;
      res[0] |= d << (24 - 8 * L);
      res[1] = res[1] - cum;
      res[2] += cum;
    }
    __syncthreads();
  }
}

// ============================================================================
// K1: h = relu(feats @ W_b + b_b)  fp32, 64x64 tile, 4x4 acc/thread, BK=16.
// EXACT R18 version (measured 157us, VGPR=40, occ 37%, FETCH 69MB). FROZEN:
// R15 (dbuf) spilled acc -> 10x; R19 (B-from-L2) regressed 30%; R18 is the
// measured local optimum for this toolchain. XCD remap keeps A L2-resident.
// Also zero-inits hist4/cnt/validw (block 0 only).
// ============================================================================
__global__ __launch_bounds__(256, 4) void k_gemm1(
    const float* __restrict__ A, const float* __restrict__ W,
    const float* __restrict__ bias, float* __restrict__ H,
    U32* __restrict__ hist4, U32* __restrict__ cnt, U32* __restrict__ validw32)
{
  int t = threadIdx.x;
  if (blockIdx.x == 0) {
    hist4[t] = 0; hist4[t + 256] = 0; hist4[t + 512] = 0; hist4[t + 768] = 0;
    if (t < 64)  cnt[t] = 0u;
    if (t < 188) validw32[t] = 0;
  }
  int bid = blockIdx.x;
  int c = bid & 7;                 // XCD under round-robin dispatch
  int s = bid >> 3;                // 0..159
  int x = s / 20;                  // 0..7   column block
  int yy = c * 20 + (s % 20);      // 0..159 row block; XCD-local A slab
  if (yy >= 157) return;           // 24 dead blocks
  __shared__ float As[16][68];    // [k][m], pad keeps 16B alignment
  __shared__ float Bs[16][68];    // [k][n]
  int m0 = yy * 64, n0 = x * 64;
  int tm = t >> 4, tn = t & 15;
  int ar = t >> 2, ac = (t & 3) << 2;   // A stage: row ar, cols ac..ac+3
  int bk = t >> 4, bc = (t & 15) << 2;  // B stage: row bk, cols bc..bc+3
  float acc[4][4];
#pragma unroll
  for (int i = 0; i < 4; ++i)
#pragma unroll
    for (int j = 0; j < 4; ++j) acc[i][j] = 0.f;

  // prologue: first tile's loads
  int arow = m0 + ar;
  float4 a0 = make_float4(0.f,0.f,0.f,0.f);
  if (arow < NPIX) a0 = *(const float4*)&A[(size_t)arow * KDIM + ac];
  float4 b0 = *(const float4*)&W[(size_t)bk * CBOT + n0 + bc];

  for (int k0 = 0; k0 < KDIM; k0 += 16) {
    __syncthreads();                 // prior FMA readers done
    As[ac+0][ar] = a0.x; As[ac+1][ar] = a0.y;
    As[ac+2][ar] = a0.z; As[ac+3][ar] = a0.w;
    *(float4*)&Bs[bk][bc] = b0;
    __syncthreads();
    if (k0 + 16 < KDIM) {            // issue next-tile loads BEFORE FMA loop
      int kn = k0 + 16;
      if (arow < NPIX) a0 = *(const float4*)&A[(size_t)arow * KDIM + kn + ac];
      b0 = *(const float4*)&W[(size_t)(kn + bk) * CBOT + n0 + bc];
    }
#pragma unroll
    for (int kk = 0; kk < 16; ++kk) {
      float4 av = *(float4*)&As[kk][tm*4];       // 16-lane broadcast groups
      float4 bv = *(float4*)&Bs[kk][tn*4];       // 2-way aliasing: free
      float am[4] = {av.x, av.y, av.z, av.w};
      float bm[4] = {bv.x, bv.y, bv.z, bv.w};
#pragma unroll
      for (int i = 0; i < 4; ++i)
#pragma unroll
        for (int j = 0; j < 4; ++j)
          acc[i][j] = fmaf(am[i], bm[j], acc[i][j]);
    }
  }
  float4 bb = *(const float4*)&bias[n0 + tn*4];
  float bm[4] = {bb.x, bb.y, bb.z, bb.w};
#pragma unroll
  for (int i = 0; i < 4; ++i) {
    int r = m0 + tm*4 + i;
    if (r < NPIX) {
      float4 o;
      o.x = fmaxf(acc[i][0] + bm[0], 0.f);
      o.y = fmaxf(acc[i][1] + bm[1], 0.f);
      o.z = fmaxf(acc[i][2] + bm[2], 0.f);
      o.w = fmaxf(acc[i][3] + bm[3], 0.f);
      *(float4*)&H[(size_t)r * CBOT + n0 + tn*4] = o;
    }
  }
}

// ============================================================================
// K2: cls = sigmoid(h@W_cls+b_cls), reg = h@W_reg+b_reg.
// R20 layout: 14 pixels x 18 threads (9 cls scalar + 9 reg float4 threads).
// Per-output FMA chains ascending-k -> outputs bitwise unchanged.
// ============================================================================
__global__ __launch_bounds__(256) void k_heads(
    const float* __restrict__ H, const float* __restrict__ Wc,
    const float* __restrict__ bc, const float* __restrict__ Wr,
    const float* __restrict__ br, float* __restrict__ outCls,
    float* __restrict__ outReg)
{
  __shared__ float hs[HP][516];
  int t = threadIdx.x;
  int p0 = blockIdx.x * HP;
  for (int q = t; q < HP * 128; q += 256) {
    int row = q >> 7, off = (q & 127) << 2;
    if (p0 + row < NPIX)
      *(float4*)&hs[row][off] = *(const float4*)&H[(size_t)(p0 + row) * CBOT + off];
  }
  __syncthreads();
  if (t < HP * 18) {
    int pl = t / 18, c = t % 18;
    int p = p0 + pl;
    if (p < NPIX) {
      const float* hrow = hs[pl];
      if (c < 9) {                       // cls channel c (scalar chain)
        float s = 0.f;
        for (int k = 0; k < CBOT; k += 4) {
          float4 hv = *(const float4*)&hrow[k];
          s = fmaf(hv.x, Wc[(size_t)(k+0)*9 + c], s);
          s = fmaf(hv.y, Wc[(size_t)(k+1)*9 + c], s);
          s = fmaf(hv.z, Wc[(size_t)(k+2)*9 + c], s);
          s = fmaf(hv.w, Wc[(size_t)(k+3)*9 + c], s);
        }
        s += bc[c];
        outCls[(size_t)p*9 + c] = 1.f / (1.f + expf(-s));
      } else {                           // reg channels g..g+3 (float4 loads)
        int g = (c - 9) << 2;
        float4 s4 = make_float4(0.f, 0.f, 0.f, 0.f);
        for (int k = 0; k < CBOT; k += 4) {
          float4 hv = *(const float4*)&hrow[k];
          float4 w0 = *(const float4*)&Wr[(size_t)(k+0)*36 + g];
          float4 w1 = *(const float4*)&Wr[(size_t)(k+1)*36 + g];
          float4 w2 = *(const float4*)&Wr[(size_t)(k+2)*36 + g];
          float4 w3 = *(const float4*)&Wr[(size_t)(k+3)*36 + g];
          s4.x = fmaf(hv.x, w0.x, s4.x); s4.y = fmaf(hv.x, w0.y, s4.y);
          s4.z = fmaf(hv.x, w0.z, s4.z); s4.w = fmaf(hv.x, w0.w, s4.w);
          s4.x = fmaf(hv.y, w1.x, s4.x); s4.y = fmaf(hv.y, w1.y, s4.y);
          s4.z = fmaf(hv.y, w1.z, s4.z); s4.w = fmaf(hv.y, w1.w, s4.w);
          s4.x = fmaf(hv.z, w2.x, s4.x); s4.y = fmaf(hv.z, w2.y, s4.y);
          s4.z = fmaf(hv.z, w2.z, s4.z); s4.w = fmaf(hv.z, w2.w, s4.w);
          s4.x = fmaf(hv.w, w3.x, s4.x); s4.y = fmaf(hv.w, w3.y, s4.y);
          s4.z = fmaf(hv.w, w3.z, s4.z); s4.w = fmaf(hv.w, w3.w, s4.w);
        }
        float4 bb = *(const float4*)&br[g];
        s4.x += bb.x; s4.y += bb.y; s4.z += bb.z; s4.w += bb.w;
        *(float4*)&outReg[(size_t)p*36 + g] = s4;
      }
    }
  }
}

// ============================================================================
// K3: decode boxes, size filter, sortable keys, level-0 histogram
// ============================================================================
__global__ __launch_bounds__(256) void k_decode(
    const float* __restrict__ outCls, const float* __restrict__ outReg,
    const float* __restrict__ ancs, float* __restrict__ boxes,
    U32* __restrict__ keys, U32* __restrict__ hist4)
{
  __shared__ U32 lh[256];
  int t = threadIdx.x;
  int tid = blockIdx.x * 256 + t;
  lh[t] = 0;
  __syncthreads();
  if (tid < NBOX) {
    float sc = outCls[tid];
    float4 of = *(const float4*)&outReg[(size_t)tid*4];
    float4 an = *(const float4*)&ancs[(size_t)tid*4];
    float cx = an.x + of.x * an.z;
    float cy = an.y + of.y * an.w;
    float ww = an.z * expf(of.z);
    float hh = an.w * expf(of.w);
    float x1 = fminf(fmaxf(cx - ww * 0.5f, 0.f), 1.f);
    float y1 = fminf(fmaxf(cy - hh * 0.5f, 0.f), 1.f);
    float x2 = fminf(fmaxf(cx + ww * 0.5f, 0.f), 1.f);
    float y2 = fminf(fmaxf(cy + hh * 0.5f, 0.f), 1.f);
    bool ok = ((x2 - x1) * 100.f >= 1.f) && ((y2 - y1) * 100.f >= 1.f);
    float msc = ok ? sc : -1.f;
    U32 u = __float_as_uint(msc);
    U32 key = (u & 0x80000000u) ? ~u : (u | 0x80000000u);
    keys[tid] = key;
    *(float4*)&boxes[(size_t)tid*4] = make_float4(x1, y1, x2, y2);
    atomicAdd(&lh[key >> 24], 1u);
  }
  __syncthreads();
  if (lh[t]) atomicAdd(&hist4[t], lh[t]);
}

// ============================================================================
// K5: filtered histogram for levels 1..3; prefix recomputed locally.
// ============================================================================
__global__ __launch_bounds__(256) void k_hist(
    const U32* __restrict__ keys, U32* __restrict__ hist4, int level)
{
  __shared__ U32 lh[256];
  __shared__ U32 sfx[256];
  __shared__ U32 res[4];
  int t = threadIdx.x;
  scan_levels(hist4, level, t, lh, sfx, res);
  U32 prefix = res[0];
  lh[t] = 0;
  __syncthreads();
  int tid = blockIdx.x * 256 + t;
  if (tid < NBOX) {
    U32 k = keys[tid];
    int shift = 32 - 8*level;
    if ((k >> shift) == (prefix >> shift)) {
      U32 bin = (k >> (24 - 8*level)) & 0xFFu;
      atomicAdd(&lh[bin], 1u);
    }
  }
  __syncthreads();
  if (lh[t]) atomicAdd(&hist4[level * 256 + t], lh[t]);
}

// ============================================================================
// K6: compact: keys > T -> sel; keys == T -> tie buffer. T local.
// (Last reader of keys[]; rank[] overlays that region afterwards.)
// ============================================================================
__global__ __launch_bounds__(256) void k_compact(
    const U32* __restrict__ keys, const U32* __restrict__ hist4,
    U32* __restrict__ cnt, U64* __restrict__ sel, U32* __restrict__ tiebuf)
{
  __shared__ U32 lh[256];
  __shared__ U32 sfx[256];
  __shared__ U32 res[4];
  int t = threadIdx.x;
  scan_levels(hist4, 4, t, lh, sfx, res);
  U32 T = res[0];
  int tid = blockIdx.x * 256 + t;
  if (tid >= NBOX) return;
  U32 k = keys[tid];
  if (k > T) {
    U32 p = atomicAdd(&cnt[8], 1u);
    sel[p] = ((U64)k << 32) | (U64)(0xFFFFFFFFu - (U32)tid);
  } else if (k == T) {
    U32 p = atomicAdd(&cnt[9], 1u);
    if (p < NTIE) tiebuf[p] = (U32)tid;
  }
}

// ============================================================================
// K7: resolve ==T ties by smallest index; need/cgt/T local.
// Also zeroes rank[6000] (overlaid on dead keys region) for k_rankp.
// ============================================================================
__global__ __launch_bounds__(256) void k_ties(
    const U32* __restrict__ hist4, U32* __restrict__ cnt,
    const U32* __restrict__ tiebuf, U64* __restrict__ sel,
    U32* __restrict__ rank)
{
  __shared__ U32 lh[256];
  __shared__ U32 sfx[256];
  __shared__ U32 res[4];
  __shared__ U32 tb[NTIE];
  int t = threadIdx.x;
  for (int j = t; j < PRE_N; j += 256) rank[j] = 0;   // zero rank array
  scan_levels(hist4, 4, t, lh, sfx, res);
  U32 T    = res[0];
  U32 need = res[1];
  U32 cgt  = res[2];
  U32 m = cnt[9]; if (m > (U32)NTIE) m = (U32)NTIE;
  for (U32 j = t; j < m; j += 256) tb[j] = tiebuf[j];
  __syncthreads();
  for (U32 x = t; x < m; x += 256) {
    U32 my = tb[x];
    U32 r = 0;
    for (U32 j = 0; j < m; ++j) r += (tb[j] < my) ? 1u : 0u;
    if (r < need) sel[cgt + r] = ((U64)T << 32) | (U64)(0xFFFFFFFFu - my);
  }
}

// ============================================================================
// K8a: partial ranks. Grid (24, 8): block (bi,bj) compares candidates
// [256*bi, 256*bi+256) against column slice [750*bj, 750*bj+750) staged in
// LDS; integer atomicAdd partials (order-invariant => deterministic).
// ============================================================================
__global__ __launch_bounds__(256) void k_rankp(
    const U64* __restrict__ sel, U32* __restrict__ rank)
{
  __shared__ __align__(16) U64 ss[CSPL + 2];   // +2 pad (zeros, never > C)
  int t = threadIdx.x;
  int j0 = blockIdx.y * CSPL;
  for (int j = t; j < CSPL + 2; j += 256)
    ss[j] = (j < CSPL) ? sel[j0 + j] : 0ull;
  __syncthreads();
  int i = blockIdx.x * 256 + t;
  if (i >= PRE_N) return;
  U64 C = sel[i];
  int r = 0;
  for (int j = 0; j < CSPL; j += 4) {          // 750 = 187*4 + 2: pad covers
    ulonglong2 v0 = *(const ulonglong2*)&ss[j];
    ulonglong2 v1 = *(const ulonglong2*)&ss[j + 2];
    r += (int)(v0.x > C) + (int)(v0.y > C) + (int)(v1.x > C) + (int)(v1.y > C);
  }
  if (r) atomicAdd(&rank[i], (U32)r);
}

// ============================================================================
// K8b: placement by final rank -> sorted boxes + packed valid bits.
// ============================================================================
__global__ __launch_bounds__(256) void k_place(
    const U64* __restrict__ sel, const U32* __restrict__ rank,
    const float* __restrict__ boxes, float* __restrict__ sboxes,
    U64* __restrict__ validw)
{
  int i = blockIdx.x * 256 + threadIdx.x;
  if (i >= PRE_N) return;
  U64 C = sel[i];
  U32 r = rank[i];
  U32 key = (U32)(C >> 32);
  U32 idx = 0xFFFFFFFFu - (U32)(C & 0xFFFFFFFFull);
  *(float4*)&sboxes[(size_t)r*4] = *(const float4*)&boxes[(size_t)idx*4];
  if (key & 0x80000000u)
    atomicOr(&validw[r >> 6], 1ull << (r & 63));
}

// ============================================================================
// K9: IoU > 0.7 bitmask, COLUMN-word-major, upper triangle + diagonal only.
// Rows 6000..6015 in touched blocks written as 0.
// ============================================================================
__global__ __launch_bounds__(256) void k_mask(
    const float* __restrict__ sboxes, U64* __restrict__ maskT)
{
  int cw = blockIdx.x, rg = blockIdx.y;
  if (rg < cw) return;                       // lower triangle unused by NMS
  int t = threadIdx.x;
  int lane = t & 63, wv = t >> 6;
  int col = cw * 64 + lane;
  int cc = (col < PRE_N) ? col : (PRE_N - 1);
  float4 cb = *(const float4*)&sboxes[(size_t)cc*4];
  float areaC = (cb.z - cb.x) * (cb.w - cb.y);
  bool colok = (col < PRE_N);
  for (int rr = wv; rr < 64; rr += 4) {
    int row = rg * 64 + rr;
    U64 word = 0;
    if (row < PRE_N) {
      float4 rb = *(const float4*)&sboxes[(size_t)row*4];
      float areaR = (rb.z - rb.x) * (rb.w - rb.y);
      float ix1 = fmaxf(rb.x, cb.x), iy1 = fmaxf(rb.y, cb.y);
      float ix2 = fminf(rb.z, cb.z), iy2 = fminf(rb.w, cb.w);
      float inter = fmaxf(ix2 - ix1, 0.f) * fmaxf(iy2 - iy1, 0.f);
      float uni = areaR + areaC - inter;
      float iou = inter / fmaxf(uni, 1e-9f);
      word = __ballot(colok && (iou > 0.7f));
    }
    if (lane == 0) maskT[(size_t)cw * MROWS + row] = word;
  }
}

// ============================================================================
// K10: sequential-equivalent NMS — 8 WAVES, barrier phases, hoisted apply
// loads (static 12-group unroll: R22's runtime-bounded variant regressed,
// guard-dependence defeated load clustering), fused proposal output.
// Bitwise-deterministic, reference scan order.
// ============================================================================
__global__ __launch_bounds__(512, 1) void k_nms(
    const U64* __restrict__ maskT, const U64* __restrict__ validw,
    const float* __restrict__ sboxes, float* __restrict__ prop)
{
  __shared__ U32 sup[MROWS];
  __shared__ U64 vws[NWORD];
  __shared__ U64 kwS[NWORD];
  __shared__ U32 pre[NWORD + 1];
  __shared__ U64 kwsh;
  int t = threadIdx.x;                       // 0..511
  int wave = t >> 6, lane = t & 63;
  for (int i = t; i < MROWS; i += 512) sup[i] = 0;
  if (t < NWORD) vws[t] = validw[t];
  U64 low = (lane == 0) ? 0ull : (~0ull >> (64 - lane));
  U64 intra = (wave == 0) ? maskT[lane] : 0ull;   // chunk 0 diagonal word
  __syncthreads();
  for (int c = 0; c < NWORD; ++c) {
    const U64* colp = maskT + (size_t)c * MROWS;
    int base = (c + 1) * 64;
    // ---- hoisted apply loads (independent of decide) ----
    U64 m[12];                               // 12*512 = 6144 >= max rows
#pragma unroll
    for (int q = 0; q < 12; ++q) {
      int i = base + q * 512 + t;
      int ic = (i > MROWS - 1) ? (MROWS - 1) : i;
      m[q] = colp[ic];
    }
    if (wave == 0) {
      // ---- decide (wave-0 local; ballots are per-wave) ----
      U64 vw = vws[c];
      bool alive = (((vw >> lane) & 1ull) != 0ull) && (sup[c * 64 + lane] == 0u);
      U64 aliveW = __ballot(alive);
      bool myconf = alive && ((intra & aliveW & low) != 0ull);
      U64 confW = __ballot(myconf);
      U64 keep = aliveW & ~confW;            // non-conflicted alive are kept
      U64 rem = confW;                       // resolve conflicted ascending
      while (rem) {
        int b = __ffsll((unsigned long long)rem) - 1;
        rem &= rem - 1;
        U64 Z = __ballot((intra & keep & low) == 0ull);
        if ((Z >> b) & 1ull) keep |= (1ull << b);
      }
      if (lane == 0) { kwS[c] = keep; kwsh = keep; }
      if (c + 1 < NWORD)                     // prefetch next diagonal word
        intra = maskT[(size_t)(c + 1) * MROWS + (c + 1) * 64 + lane];
    }
    __syncthreads();                         // kwsh + sup reads ordered
    U64 keep = kwsh;                         // 0 -> stores self-disable
#pragma unroll
    for (int q = 0; q < 12; ++q) {
      int i = base + q * 512 + t;
      if (i < PRE_N && (m[q] & keep)) sup[i] = 1u;
    }
    __syncthreads();                         // sup[] complete before decide c+1
  }
  // ---- fused proposal output ----
  if (t == 0) {
    U32 s = 0;
    for (int w = 0; w < NWORD; ++w) { pre[w] = s; s += (U32)__popcll(kwS[w]); }
    pre[NWORD] = s;
  }
  for (int x = t; x < POST_N * 4; x += 512) prop[x] = 0.f;
  __syncthreads();
  for (int i = t; i < PRE_N; i += 512) {
    int w = i >> 6, b = i & 63;
    if ((kwS[w] >> b) & 1ull) {
      U64 lowb = (b == 0) ? 0ull : (~0ull >> (64 - b));
      U32 r = pre[w] + (U32)__popcll(kwS[w] & lowb);
      if (r < POST_N)
        *(float4*)&prop[(size_t)r*4] = *(const float4*)&sboxes[(size_t)i*4];
    }
  }
}

// ============================================================================
extern "C" void kernel_launch(void* const* d_in, const int* in_sizes, int n_in,
                              void* d_out, int out_size, void* d_ws, size_t ws_size,
                              hipStream_t stream)
{
  (void)in_sizes; (void)n_in; (void)out_size;
  if (ws_size < WS_NEED) return;   // scratch too small; bail safely

  const float* feats = (const float*)d_in[0];
  const float* ancs  = (const float*)d_in[1];
  const float* W_b   = (const float*)d_in[3];
  const float* b_b   = (const float*)d_in[4];
  const float* W_cls = (const float*)d_in[5];
  const float* b_cls = (const float*)d_in[6];
  const float* W_reg = (const float*)d_in[7];
  const float* b_reg = (const float*)d_in[8];

  float* out    = (float*)d_out;
  float* outCls = out;                 // 90000
  float* outReg = out + 90000;         // 360000
  float* prop   = out + 450000;        // 1200

  char* ws = (char*)d_ws;
  float* H      = (float*)(ws + OFF_H);
  float* boxes  = (float*)(ws + OFF_BOXES);
  U32*   keys   = (U32*)  (ws + OFF_KEYS);
  U32*   rankb  = (U32*)  (ws + OFF_KEYS);   // overlays keys (dead post-compact)
  U64*   maskT  = (U64*)  (ws + OFF_MASKT);
  U64*   sel    = (U64*)  (ws + OFF_SEL);
  float* sboxes = (float*)(ws + OFF_SBOX);
  U64*   validw = (U64*)  (ws + OFF_VALIDW);
  U32*   cnt    = (U32*)  (ws + OFF_CNT);
  U32*   hist4  = (U32*)  (ws + OFF_HIST4);
  U32*   tiebuf = (U32*)  (ws + OFF_TIE);

  k_gemm1<<<dim3(1280), dim3(256), 0, stream>>>(feats, W_b, b_b, H,
                                                hist4, cnt, (U32*)validw);
  k_heads<<<dim3((NPIX + HP - 1) / HP), dim3(256), 0, stream>>>(
      H, W_cls, b_cls, W_reg, b_reg, outCls, outReg);
  k_decode<<<dim3(352), dim3(256), 0, stream>>>(outCls, outReg, ancs,
                                                boxes, keys, hist4);
  for (int lv = 1; lv <= 3; ++lv)
    k_hist<<<dim3(352), dim3(256), 0, stream>>>(keys, hist4, lv);
  k_compact<<<dim3(352), dim3(256), 0, stream>>>(keys, hist4, cnt, sel, tiebuf);
  k_ties<<<dim3(1), dim3(256), 0, stream>>>(hist4, cnt, tiebuf, sel, rankb);
  k_rankp<<<dim3(24, 8), dim3(256), 0, stream>>>(sel, rankb);
  k_place<<<dim3(24), dim3(256), 0, stream>>>(sel, rankb, boxes, sboxes, validw);
  k_mask<<<dim3(94, 94), dim3(256), 0, stream>>>(sboxes, maskT);
  k_nms<<<dim3(1), dim3(512), 0, stream>>>(maskT, validw, sboxes, prop);
}